// Round 5
// baseline (79.526 us; speedup 1.0000x reference)
//
#include <hip/hip_runtime.h>

#define L2_REG 0.01f
#define NTOT 16384
#define K    8          // WGs (one per XCD)
#define NBL  4096       // local bins per WG
#define GB   (K * NBL)  // 32768 global fine bins; mean occupancy 0.5
#define CAP  3072       // per-WG chunk capacity (mean 2048, +24 sigma)
#define NT   1024
#define MAGIC 0x5A17C0DE  // != any plausible fill-poison dword pattern

// R14: R13's compute body, single node. No-init cross-WG reduction:
//   publish (T,E,WS) via atomicExch (coherent point), __threadfence,
//   atomicExch(flag[wg], MAGIC); then EVERY WG polls all 8 flags and
//   writes the bitwise-identical final scalar (benign same-value race).
// Publish-before-poll => no cyclic wait => deadlock-free for any schedule
// of the 8 co-resident WGs. Per-iteration ws poison clears stale MAGICs
// between graph replays (observed: 40us fill before every replay).
// e packed into rp mantissa LSB (<=1 ulp; benched absmax 0.0 since R11).

__global__ __launch_bounds__(NT) void cox_all(const float* __restrict__ rp,
                                              const float* __restrict__ y,
                                              const int* __restrict__ e,
                                              const float* __restrict__ W,
                                              float* __restrict__ pubT,
                                              float* __restrict__ pubE,
                                              float* __restrict__ pubW,
                                              int* __restrict__ flag,
                                              float* __restrict__ out) {
    __shared__ __align__(16) float2 s_ye[CAP];   // 24 KB sorted chunk
    __shared__ __align__(16) int    s_off[NBL];  // 16 KB counts->offsets->cursor
    __shared__ int   s_isc[16];                  // scan wave partials (bin counts)
    __shared__ int   s_i1[16];                   // below-count wave partials
    __shared__ float s_f1[16], s_f2[16];         // hi_sum / wsum wave partials
    __shared__ float s_sc[16];                   // suffix-scan wave partials
    __shared__ float s_r0[16], s_r1[16];         // term / ecnt wave partials
    __shared__ int   s_OFF;
    __shared__ float s_SUF, s_WS;

    const int t = threadIdx.x, wg = blockIdx.x;
    const int lane = t & 63, wave = t >> 6;

    *reinterpret_cast<int4*>(&s_off[4 * t]) = make_int4(0, 0, 0, 0);

    // ---- load all inputs (16 elem/thread, coalesced float4); pack e into r LSB ----
    float yv[16], rk[16];
    int   bv[16];
    {
        const float4* y4 = reinterpret_cast<const float4*>(y);
        const float4* r4 = reinterpret_cast<const float4*>(rp);
        const int4*   e4 = reinterpret_cast<const int4*>(e);
#pragma unroll
        for (int k = 0; k < 4; ++k) {
            const float4 yy = y4[k * NT + t];
            const float4 rr = r4[k * NT + t];
            const int4   ee = e4[k * NT + t];
            yv[4*k+0] = yy.x; yv[4*k+1] = yy.y; yv[4*k+2] = yy.z; yv[4*k+3] = yy.w;
            rk[4*k+0] = __int_as_float((__float_as_int(rr.x) & ~1) | (ee.x & 1));
            rk[4*k+1] = __int_as_float((__float_as_int(rr.y) & ~1) | (ee.y & 1));
            rk[4*k+2] = __int_as_float((__float_as_int(rr.z) & ~1) | (ee.z & 1));
            rk[4*k+3] = __int_as_float((__float_as_int(rr.w) & ~1) | (ee.w & 1));
        }
    }
#pragma unroll
    for (int k = 0; k < 16; ++k) {
        int g = (int)(yv[k] * (float)GB);
        bv[k] = min(max(g, 0), GB - 1);
    }
    // ---- ||W||^2 partial: own 64 KB slice ----
    float wsum = 0.f;
    {
        const float4* W4 = reinterpret_cast<const float4*>(W) + wg * 4096;
#pragma unroll
        for (int m = 0; m < 4; ++m) {
            const float4 w = W4[m * NT + t];
            wsum = fmaf(w.x, w.x, wsum); wsum = fmaf(w.y, w.y, wsum);
            wsum = fmaf(w.z, w.z, wsum); wsum = fmaf(w.w, w.w, wsum);
        }
    }
    __syncthreads();                       // s_off zeroed

    // ---- histogram own range + cross-WG scalars (below-count, above-exp-sum) ----
    const int lo = wg * NBL, hi = lo + NBL;
    int   bl = 0;
    float hs = 0.f;
#pragma unroll
    for (int k = 0; k < 16; ++k) {
        const unsigned lb = (unsigned)(bv[k] - lo);
        if (lb < NBL) atomicAdd(&s_off[lb], 1);
        bl += (bv[k] < lo) ? 1 : 0;
        const float ex = __expf(rk[k]);
        hs = fmaf((bv[k] >= hi) ? 1.f : 0.f, ex, hs);
    }
#pragma unroll
    for (int o = 32; o; o >>= 1) {
        bl   += __shfl_down(bl,   o, 64);
        hs   += __shfl_down(hs,   o, 64);
        wsum += __shfl_down(wsum, o, 64);
    }
    if (lane == 0) { s_i1[wave] = bl; s_f1[wave] = hs; s_f2[wave] = wsum; }
    __syncthreads();                       // atomics + partials done

    // ---- exact int scan: counts -> exclusive offsets X[b] (4 bins/thread) ----
    const int4 c4 = *reinterpret_cast<const int4*>(&s_off[4 * t]);
    const int cs = c4.x + c4.y + c4.z + c4.w;
    int ci = cs;
#pragma unroll
    for (int o = 1; o < 64; o <<= 1) {
        const int p = __shfl_up(ci, o, 64);
        if (lane >= o) ci += p;
    }
    if (lane == 63) s_isc[wave] = ci;
    __syncthreads();
    if (t < 16) {
        int v = s_isc[t];
#pragma unroll
        for (int o = 1; o < 16; o <<= 1) {
            const int p = __shfl_up(v, o, 64);
            if (lane >= o) v += p;
        }
        s_isc[t] = v;
    }
    if (t == 64) {                         // wave 1 sums cross-WG scalars in parallel
        int   O = 0; float S = 0.f, Wp = 0.f;
#pragma unroll
        for (int w = 0; w < 16; ++w) { O += s_i1[w]; S += s_f1[w]; Wp += s_f2[w]; }
        s_OFF = O; s_SUF = S; s_WS = Wp;
    }
    __syncthreads();
    {
        const int base = ci - cs + (wave ? s_isc[wave - 1] : 0);
        s_off[4*t+0] = base;
        s_off[4*t+1] = base + c4.x;
        s_off[4*t+2] = base + c4.x + c4.y;
        s_off[4*t+3] = base + c4.x + c4.y + c4.z;
    }
    __syncthreads();                       // offsets ready

    // ---- counting-sort scatter (cursor atomics; s_off becomes X[b+1]) ----
#pragma unroll
    for (int k = 0; k < 16; ++k) {
        const unsigned lb = (unsigned)(bv[k] - lo);
        if (lb < NBL) {
            const int pos = atomicAdd(&s_off[lb], 1);
            if (pos < CAP) s_ye[pos] = make_float2(yv[k], rk[k]);
        }
    }
    __syncthreads();

    // ---- insertion sort own 4 bins (mean c=0.5: trivial) ----
    {
        int start = t ? s_off[4 * t - 1] : 0;
#pragma unroll
        for (int c = 0; c < 4; ++c) {
            const int k1 = s_off[4 * t + c];
            for (int i = start + 1; i < k1; ++i) {
                const float2 v = s_ye[i];
                int j = i - 1;
                while (j >= start && s_ye[j].x > v.x) { s_ye[j + 1] = s_ye[j]; --j; }
                s_ye[j + 1] = v;
            }
            start = k1;
        }
    }
    __syncthreads();

    // ---- local suffix walk: thread owns local positions [3t, 3t+3). ----
    const int n = min(s_isc[15], CAP);
    const int OFF = s_OFF;
    float rv[3], ei[3];
    float csum = 0.f;
#pragma unroll
    for (int j = 0; j < 3; ++j) {
        const int p = 3 * t + j;
        rv[j] = 0.f; ei[j] = 0.f;
        if (p < n) { const float2 v = s_ye[p]; rv[j] = v.y; ei[j] = __expf(v.y); csum += ei[j]; }
    }
    float s = csum;
#pragma unroll
    for (int o = 1; o < 64; o <<= 1) {
        const float v = __shfl_down(s, o, 64);
        if (lane + o < 64) s += v;
    }
    if (lane == 0) s_sc[wave] = s;
    __syncthreads();
    if (t < 16) {
        float v = s_sc[t];
#pragma unroll
        for (int o = 1; o < 16; o <<= 1) {
            const float p = __shfl_down(v, o, 64);
            if (t + o < 16) v += p;
        }
        s_sc[t] = v;
    }
    __syncthreads();
    float run = (s - csum) + ((wave < 15) ? s_sc[wave + 1] : 0.f) + s_SUF;
    float term = 0.f, ecnt = 0.f;
#pragma unroll
    for (int j = 2; j >= 0; --j) {
        const int p = 3 * t + j;
        if (p < n) {
            run += ei[j];
            if (__float_as_int(rv[j]) & 1) {
                term += rv[j] - __logf(__fdividef(run, (float)(NTOT - (OFF + p))));
                ecnt += 1.f;
            }
        }
    }
#pragma unroll
    for (int o = 32; o; o >>= 1) {
        term += __shfl_down(term, o, 64);
        ecnt += __shfl_down(ecnt, o, 64);
    }
    if (lane == 0) { s_r0[wave] = term; s_r1[wave] = ecnt; }
    __syncthreads();

    // ---- no-init cross-WG reduction: publish -> fence -> flag -> poll-all ----
    if (t == 0) {
        float T = 0.f, E = 0.f;
#pragma unroll
        for (int w = 0; w < 16; ++w) { T += s_r0[w]; E += s_r1[w]; }
        atomicExch(&pubT[wg], T);          // values live at the coherent point
        atomicExch(&pubE[wg], E);
        atomicExch(&pubW[wg], s_WS);
        __threadfence();
        atomicExch(&flag[wg], MAGIC);      // publish-BEFORE-poll: deadlock-free
        for (int k = 0; k < K; ++k)
            while (atomicAdd(&flag[k], 0) != MAGIC) {}
        __threadfence();
        float TT = 0.f, EE = 0.f, WS = 0.f;
#pragma unroll
        for (int k = 0; k < K; ++k) {      // fixed order => identical bits in all WGs
            TT += atomicAdd(&pubT[k], 0.f);
            EE += atomicAdd(&pubE[k], 0.f);
            WS += atomicAdd(&pubW[k], 0.f);
        }
        out[0] = -TT / EE + L2_REG * sqrtf(WS);   // benign same-value race
    }
}

extern "C" void kernel_launch(void* const* d_in, const int* in_sizes, int n_in,
                              void* d_out, int out_size, void* d_ws, size_t ws_size,
                              hipStream_t stream) {
    (void)in_sizes; (void)n_in; (void)out_size; (void)ws_size;
    float* pubT = (float*)d_ws;            // [8]
    float* pubE = pubT + K;                // [8]
    float* pubW = pubE + K;                // [8]
    int*   flag = (int*)(pubW + K);        // [8]

    cox_all<<<dim3(K), dim3(NT), 0, stream>>>((const float*)d_in[0],
                                              (const float*)d_in[1],
                                              (const int*)d_in[2],
                                              (const float*)d_in[3],
                                              pubT, pubE, pubW, flag,
                                              (float*)d_out);
}

// Round 6
// 69.781 us; speedup vs baseline: 1.1396x; 1.1396x over previous
//
#include <hip/hip_runtime.h>

#define L2_REG 0.01f
#define NTOT 16384
#define K    8          // WGs (one per XCD)
#define NBL  4096       // local bins per WG
#define GB   (K * NBL)  // 32768 global fine bins; mean occupancy 0.5
#define CAP  3072       // per-WG chunk capacity (mean 2048, +24 sigma)
#define NT   1024
#define MAGIC 0x5A17C0DEu

// R15: R13/R14 compute body (absmax 0.0 proven), single node, latency-fixed
// no-init reduction. R14's 13.5us spin = 24 SERIAL far-atomic RMW reads +
// flag false-sharing from 8 pollers. Fix:
//   - payload packed into u64 words: pub2[wg]=(T,E), pubF[wg]=(WS,MAGIC)
//     (flag and WS arrive atomically together; 2 exchanges to publish)
//   - ONLY WG0 polls; its wave-0 lanes 0..7 poll/read the 8 WGs' words
//     CONCURRENTLY (1 round-trip instead of 16 serial), shuffle-tree fold
//   - other WGs publish + retire (zero polling traffic)
// Publish-before-poll => deadlock-free; per-iteration ws poison clears MAGICs.

__global__ __launch_bounds__(NT) void cox_all(const float* __restrict__ rp,
                                              const float* __restrict__ y,
                                              const int* __restrict__ e,
                                              const float* __restrict__ W,
                                              unsigned long long* __restrict__ pub2,
                                              unsigned long long* __restrict__ pubF,
                                              float* __restrict__ out) {
    __shared__ __align__(16) float2 s_ye[CAP];   // 24 KB sorted chunk
    __shared__ __align__(16) int    s_off[NBL];  // 16 KB counts->offsets->cursor
    __shared__ int   s_isc[16];
    __shared__ int   s_i1[16];
    __shared__ float s_f1[16], s_f2[16];
    __shared__ float s_sc[16];
    __shared__ float s_r0[16], s_r1[16];
    __shared__ int   s_OFF;
    __shared__ float s_SUF, s_WS;

    const int t = threadIdx.x, wg = blockIdx.x;
    const int lane = t & 63, wave = t >> 6;

    *reinterpret_cast<int4*>(&s_off[4 * t]) = make_int4(0, 0, 0, 0);

    // ---- load all inputs (16 elem/thread, coalesced float4); pack e into r LSB ----
    float yv[16], rk[16];
    int   bv[16];
    {
        const float4* y4 = reinterpret_cast<const float4*>(y);
        const float4* r4 = reinterpret_cast<const float4*>(rp);
        const int4*   e4 = reinterpret_cast<const int4*>(e);
#pragma unroll
        for (int k = 0; k < 4; ++k) {
            const float4 yy = y4[k * NT + t];
            const float4 rr = r4[k * NT + t];
            const int4   ee = e4[k * NT + t];
            yv[4*k+0] = yy.x; yv[4*k+1] = yy.y; yv[4*k+2] = yy.z; yv[4*k+3] = yy.w;
            rk[4*k+0] = __int_as_float((__float_as_int(rr.x) & ~1) | (ee.x & 1));
            rk[4*k+1] = __int_as_float((__float_as_int(rr.y) & ~1) | (ee.y & 1));
            rk[4*k+2] = __int_as_float((__float_as_int(rr.z) & ~1) | (ee.z & 1));
            rk[4*k+3] = __int_as_float((__float_as_int(rr.w) & ~1) | (ee.w & 1));
        }
    }
#pragma unroll
    for (int k = 0; k < 16; ++k) {
        int g = (int)(yv[k] * (float)GB);
        bv[k] = min(max(g, 0), GB - 1);
    }
    // ---- ||W||^2 partial: own 64 KB slice ----
    float wsum = 0.f;
    {
        const float4* W4 = reinterpret_cast<const float4*>(W) + wg * 4096;
#pragma unroll
        for (int m = 0; m < 4; ++m) {
            const float4 w = W4[m * NT + t];
            wsum = fmaf(w.x, w.x, wsum); wsum = fmaf(w.y, w.y, wsum);
            wsum = fmaf(w.z, w.z, wsum); wsum = fmaf(w.w, w.w, wsum);
        }
    }
    __syncthreads();                       // s_off zeroed

    // ---- histogram own range + cross-WG scalars (below-count, above-exp-sum) ----
    const int lo = wg * NBL, hi = lo + NBL;
    int   bl = 0;
    float hs = 0.f;
#pragma unroll
    for (int k = 0; k < 16; ++k) {
        const unsigned lb = (unsigned)(bv[k] - lo);
        if (lb < NBL) atomicAdd(&s_off[lb], 1);
        bl += (bv[k] < lo) ? 1 : 0;
        const float ex = __expf(rk[k]);
        hs = fmaf((bv[k] >= hi) ? 1.f : 0.f, ex, hs);
    }
#pragma unroll
    for (int o = 32; o; o >>= 1) {
        bl   += __shfl_down(bl,   o, 64);
        hs   += __shfl_down(hs,   o, 64);
        wsum += __shfl_down(wsum, o, 64);
    }
    if (lane == 0) { s_i1[wave] = bl; s_f1[wave] = hs; s_f2[wave] = wsum; }
    __syncthreads();                       // atomics + partials done

    // ---- exact int scan: counts -> exclusive offsets X[b] (4 bins/thread) ----
    const int4 c4 = *reinterpret_cast<const int4*>(&s_off[4 * t]);
    const int cs = c4.x + c4.y + c4.z + c4.w;
    int ci = cs;
#pragma unroll
    for (int o = 1; o < 64; o <<= 1) {
        const int p = __shfl_up(ci, o, 64);
        if (lane >= o) ci += p;
    }
    if (lane == 63) s_isc[wave] = ci;
    __syncthreads();
    if (t < 16) {
        int v = s_isc[t];
#pragma unroll
        for (int o = 1; o < 16; o <<= 1) {
            const int p = __shfl_up(v, o, 64);
            if (lane >= o) v += p;
        }
        s_isc[t] = v;
    }
    if (t == 64) {                         // wave 1 sums cross-WG scalars in parallel
        int   O = 0; float S = 0.f, Wp = 0.f;
#pragma unroll
        for (int w = 0; w < 16; ++w) { O += s_i1[w]; S += s_f1[w]; Wp += s_f2[w]; }
        s_OFF = O; s_SUF = S; s_WS = Wp;
    }
    __syncthreads();
    {
        const int base = ci - cs + (wave ? s_isc[wave - 1] : 0);
        s_off[4*t+0] = base;
        s_off[4*t+1] = base + c4.x;
        s_off[4*t+2] = base + c4.x + c4.y;
        s_off[4*t+3] = base + c4.x + c4.y + c4.z;
    }
    __syncthreads();                       // offsets ready

    // ---- counting-sort scatter (cursor atomics; s_off becomes X[b+1]) ----
#pragma unroll
    for (int k = 0; k < 16; ++k) {
        const unsigned lb = (unsigned)(bv[k] - lo);
        if (lb < NBL) {
            const int pos = atomicAdd(&s_off[lb], 1);
            if (pos < CAP) s_ye[pos] = make_float2(yv[k], rk[k]);
        }
    }
    __syncthreads();

    // ---- insertion sort own 4 bins (mean c=0.5: trivial) ----
    {
        int start = t ? s_off[4 * t - 1] : 0;
#pragma unroll
        for (int c = 0; c < 4; ++c) {
            const int k1 = s_off[4 * t + c];
            for (int i = start + 1; i < k1; ++i) {
                const float2 v = s_ye[i];
                int j = i - 1;
                while (j >= start && s_ye[j].x > v.x) { s_ye[j + 1] = s_ye[j]; --j; }
                s_ye[j + 1] = v;
            }
            start = k1;
        }
    }
    __syncthreads();

    // ---- local suffix walk: thread owns local positions [3t, 3t+3). ----
    const int n = min(s_isc[15], CAP);
    const int OFF = s_OFF;
    float rv[3], ei[3];
    float csum = 0.f;
#pragma unroll
    for (int j = 0; j < 3; ++j) {
        const int p = 3 * t + j;
        rv[j] = 0.f; ei[j] = 0.f;
        if (p < n) { const float2 v = s_ye[p]; rv[j] = v.y; ei[j] = __expf(v.y); csum += ei[j]; }
    }
    float s = csum;
#pragma unroll
    for (int o = 1; o < 64; o <<= 1) {
        const float v = __shfl_down(s, o, 64);
        if (lane + o < 64) s += v;
    }
    if (lane == 0) s_sc[wave] = s;
    __syncthreads();
    if (t < 16) {
        float v = s_sc[t];
#pragma unroll
        for (int o = 1; o < 16; o <<= 1) {
            const float p = __shfl_down(v, o, 64);
            if (t + o < 16) v += p;
        }
        s_sc[t] = v;
    }
    __syncthreads();
    float run = (s - csum) + ((wave < 15) ? s_sc[wave + 1] : 0.f) + s_SUF;
    float term = 0.f, ecnt = 0.f;
#pragma unroll
    for (int j = 2; j >= 0; --j) {
        const int p = 3 * t + j;
        if (p < n) {
            run += ei[j];
            if (__float_as_int(rv[j]) & 1) {
                term += rv[j] - __logf(__fdividef(run, (float)(NTOT - (OFF + p))));
                ecnt += 1.f;
            }
        }
    }
#pragma unroll
    for (int o = 32; o; o >>= 1) {
        term += __shfl_down(term, o, 64);
        ecnt += __shfl_down(ecnt, o, 64);
    }
    if (lane == 0) { s_r0[wave] = term; s_r1[wave] = ecnt; }
    __syncthreads();

    // ---- no-init cross-WG reduction, latency-parallel version ----
    if (wave == 0) {
        if (lane == 0) {
            float T = 0.f, E = 0.f;
#pragma unroll
            for (int w = 0; w < 16; ++w) { T += s_r0[w]; E += s_r1[w]; }
            const unsigned long long w1 =
                ((unsigned long long)__float_as_uint(T) << 32) | __float_as_uint(E);
            atomicExch(&pub2[wg], w1);
            __threadfence();               // payload visible before tag
            const unsigned long long w2 =
                ((unsigned long long)__float_as_uint(s_WS) << 32) | (unsigned long long)MAGIC;
            atomicExch(&pubF[wg], w2);
        }
        if (wg == 0) {                     // only WG0 polls; lanes 0..7 in parallel
            const bool act = lane < K;
            unsigned long long w2 = 0ULL;
            for (;;) {
                if (act) w2 = atomicAdd(&pubF[lane], 0ULL);
                if (__all(!act || ((unsigned)w2 == MAGIC))) break;
            }
            __threadfence();
            const unsigned long long w1 = act ? atomicAdd(&pub2[lane], 0ULL) : 0ULL;
            float Tk = act ? __uint_as_float((unsigned)(w1 >> 32)) : 0.f;
            float Ek = act ? __uint_as_float((unsigned)w1)         : 0.f;
            float Wk = act ? __uint_as_float((unsigned)(w2 >> 32)) : 0.f;
#pragma unroll
            for (int o = 4; o; o >>= 1) {  // lanes 8..63 carry zeros: harmless
                Tk += __shfl_down(Tk, o, 64);
                Ek += __shfl_down(Ek, o, 64);
                Wk += __shfl_down(Wk, o, 64);
            }
            if (lane == 0) out[0] = -Tk / Ek + L2_REG * sqrtf(Wk);
        }
    }
}

extern "C" void kernel_launch(void* const* d_in, const int* in_sizes, int n_in,
                              void* d_out, int out_size, void* d_ws, size_t ws_size,
                              hipStream_t stream) {
    (void)in_sizes; (void)n_in; (void)out_size; (void)ws_size;
    unsigned long long* pub2 = (unsigned long long*)d_ws;  // [8] (T,E) packed
    unsigned long long* pubF = pub2 + K;                   // [8] (WS,MAGIC) packed

    cox_all<<<dim3(K), dim3(NT), 0, stream>>>((const float*)d_in[0],
                                              (const float*)d_in[1],
                                              (const int*)d_in[2],
                                              (const float*)d_in[3],
                                              pub2, pubF, (float*)d_out);
}

// Round 7
// 68.064 us; speedup vs baseline: 1.1684x; 1.0252x over previous
//
#include <hip/hip_runtime.h>

#define L2_REG 0.01f
#define NTOT 16384
#define K    16         // WGs (2 per XCD)
#define NBL  2048       // local bins per WG
#define GB   (K * NBL)  // 32768 global fine bins (same granularity as R15)
#define CAP  1536       // per-WG chunk capacity (mean 1024, +16 sigma)
#define NT   1024
#define MAGIC 0x5A17C0DEu

// R16: R15 with K=8->16 (the only 1/K-scalable exec terms: chunk phases +
// W-slice). Same no-init latency-parallel reduction: pub2[wg]=(T,E),
// pubF[wg]=(WS,MAGIC) via atomicExch; WG0's lanes 0..15 poll all 16 words
// concurrently (1 far-atomic round-trip), shuffle-tree fold, single write.
// Publish-before-poll => deadlock-free; ws poison clears MAGICs per replay.
// e packed into rp mantissa LSB (<=1 ulp; absmax 0.0 benched since R11).

__global__ __launch_bounds__(NT) void cox_all(const float* __restrict__ rp,
                                              const float* __restrict__ y,
                                              const int* __restrict__ e,
                                              const float* __restrict__ W,
                                              unsigned long long* __restrict__ pub2,
                                              unsigned long long* __restrict__ pubF,
                                              float* __restrict__ out) {
    __shared__ __align__(16) float2 s_ye[CAP];   // 12 KB sorted chunk
    __shared__ __align__(16) int    s_off[NBL];  // 8 KB counts->offsets->cursor
    __shared__ int   s_isc[16];
    __shared__ int   s_i1[16];
    __shared__ float s_f1[16], s_f2[16];
    __shared__ float s_sc[16];
    __shared__ float s_r0[16], s_r1[16];
    __shared__ int   s_OFF;
    __shared__ float s_SUF, s_WS;

    const int t = threadIdx.x, wg = blockIdx.x;
    const int lane = t & 63, wave = t >> 6;

    *reinterpret_cast<int2*>(&s_off[2 * t]) = make_int2(0, 0);

    // ---- load all inputs (16 elem/thread, coalesced float4); pack e into r LSB ----
    float yv[16], rk[16];
    int   bv[16];
    {
        const float4* y4 = reinterpret_cast<const float4*>(y);
        const float4* r4 = reinterpret_cast<const float4*>(rp);
        const int4*   e4 = reinterpret_cast<const int4*>(e);
#pragma unroll
        for (int k = 0; k < 4; ++k) {
            const float4 yy = y4[k * NT + t];
            const float4 rr = r4[k * NT + t];
            const int4   ee = e4[k * NT + t];
            yv[4*k+0] = yy.x; yv[4*k+1] = yy.y; yv[4*k+2] = yy.z; yv[4*k+3] = yy.w;
            rk[4*k+0] = __int_as_float((__float_as_int(rr.x) & ~1) | (ee.x & 1));
            rk[4*k+1] = __int_as_float((__float_as_int(rr.y) & ~1) | (ee.y & 1));
            rk[4*k+2] = __int_as_float((__float_as_int(rr.z) & ~1) | (ee.z & 1));
            rk[4*k+3] = __int_as_float((__float_as_int(rr.w) & ~1) | (ee.w & 1));
        }
    }
#pragma unroll
    for (int k = 0; k < 16; ++k) {
        int g = (int)(yv[k] * (float)GB);
        bv[k] = min(max(g, 0), GB - 1);
    }
    // ---- ||W||^2 partial: own 32 KB slice ----
    float wsum = 0.f;
    {
        const float4* W4 = reinterpret_cast<const float4*>(W) + wg * 2048;
#pragma unroll
        for (int m = 0; m < 2; ++m) {
            const float4 w = W4[m * NT + t];
            wsum = fmaf(w.x, w.x, wsum); wsum = fmaf(w.y, w.y, wsum);
            wsum = fmaf(w.z, w.z, wsum); wsum = fmaf(w.w, w.w, wsum);
        }
    }
    __syncthreads();                       // s_off zeroed

    // ---- histogram own range + cross-WG scalars (below-count, above-exp-sum) ----
    const int lo = wg * NBL, hi = lo + NBL;
    int   bl = 0;
    float hs = 0.f;
#pragma unroll
    for (int k = 0; k < 16; ++k) {
        const unsigned lb = (unsigned)(bv[k] - lo);
        if (lb < NBL) atomicAdd(&s_off[lb], 1);
        bl += (bv[k] < lo) ? 1 : 0;
        const float ex = __expf(rk[k]);
        hs = fmaf((bv[k] >= hi) ? 1.f : 0.f, ex, hs);
    }
#pragma unroll
    for (int o = 32; o; o >>= 1) {
        bl   += __shfl_down(bl,   o, 64);
        hs   += __shfl_down(hs,   o, 64);
        wsum += __shfl_down(wsum, o, 64);
    }
    if (lane == 0) { s_i1[wave] = bl; s_f1[wave] = hs; s_f2[wave] = wsum; }
    __syncthreads();                       // atomics + partials done

    // ---- exact int scan: counts -> exclusive offsets X[b] (2 bins/thread) ----
    const int2 c2 = *reinterpret_cast<const int2*>(&s_off[2 * t]);
    const int cs = c2.x + c2.y;
    int ci = cs;
#pragma unroll
    for (int o = 1; o < 64; o <<= 1) {
        const int p = __shfl_up(ci, o, 64);
        if (lane >= o) ci += p;
    }
    if (lane == 63) s_isc[wave] = ci;
    __syncthreads();
    if (t < 16) {
        int v = s_isc[t];
#pragma unroll
        for (int o = 1; o < 16; o <<= 1) {
            const int p = __shfl_up(v, o, 64);
            if (lane >= o) v += p;
        }
        s_isc[t] = v;
    }
    if (t == 64) {                         // wave 1 folds cross-WG scalars in parallel
        int   O = 0; float S = 0.f, Wp = 0.f;
#pragma unroll
        for (int w = 0; w < 16; ++w) { O += s_i1[w]; S += s_f1[w]; Wp += s_f2[w]; }
        s_OFF = O; s_SUF = S; s_WS = Wp;
    }
    __syncthreads();
    {
        const int base = ci - cs + (wave ? s_isc[wave - 1] : 0);
        s_off[2*t+0] = base;
        s_off[2*t+1] = base + c2.x;
    }
    __syncthreads();                       // offsets ready

    // ---- counting-sort scatter (cursor atomics; s_off becomes X[b+1]) ----
#pragma unroll
    for (int k = 0; k < 16; ++k) {
        const unsigned lb = (unsigned)(bv[k] - lo);
        if (lb < NBL) {
            const int pos = atomicAdd(&s_off[lb], 1);
            if (pos < CAP) s_ye[pos] = make_float2(yv[k], rk[k]);
        }
    }
    __syncthreads();

    // ---- insertion sort own 2 bins (mean c=0.5: trivial) ----
    {
        int start = t ? s_off[2 * t - 1] : 0;
#pragma unroll
        for (int c = 0; c < 2; ++c) {
            const int k1 = s_off[2 * t + c];
            for (int i = start + 1; i < k1; ++i) {
                const float2 v = s_ye[i];
                int j = i - 1;
                while (j >= start && s_ye[j].x > v.x) { s_ye[j + 1] = s_ye[j]; --j; }
                s_ye[j + 1] = v;
            }
            start = k1;
        }
    }
    __syncthreads();

    // ---- local suffix walk: thread owns local positions [2t, 2t+2). ----
    const int n = min(s_isc[15], CAP);
    const int OFF = s_OFF;
    float rv[2], ei[2];
    float csum = 0.f;
#pragma unroll
    for (int j = 0; j < 2; ++j) {
        const int p = 2 * t + j;
        rv[j] = 0.f; ei[j] = 0.f;
        if (p < n) { const float2 v = s_ye[p]; rv[j] = v.y; ei[j] = __expf(v.y); csum += ei[j]; }
    }
    float s = csum;
#pragma unroll
    for (int o = 1; o < 64; o <<= 1) {
        const float v = __shfl_down(s, o, 64);
        if (lane + o < 64) s += v;
    }
    if (lane == 0) s_sc[wave] = s;
    __syncthreads();
    if (t < 16) {
        float v = s_sc[t];
#pragma unroll
        for (int o = 1; o < 16; o <<= 1) {
            const float p = __shfl_down(v, o, 64);
            if (t + o < 16) v += p;
        }
        s_sc[t] = v;
    }
    __syncthreads();
    float run = (s - csum) + ((wave < 15) ? s_sc[wave + 1] : 0.f) + s_SUF;
    float term = 0.f, ecnt = 0.f;
#pragma unroll
    for (int j = 1; j >= 0; --j) {
        const int p = 2 * t + j;
        if (p < n) {
            run += ei[j];                  // inclusive suffix at global rank OFF+p
            if (__float_as_int(rv[j]) & 1) {
                term += rv[j] - __logf(__fdividef(run, (float)(NTOT - (OFF + p))));
                ecnt += 1.f;
            }
        }
    }
#pragma unroll
    for (int o = 32; o; o >>= 1) {
        term += __shfl_down(term, o, 64);
        ecnt += __shfl_down(ecnt, o, 64);
    }
    if (lane == 0) { s_r0[wave] = term; s_r1[wave] = ecnt; }
    __syncthreads();

    // ---- no-init cross-WG reduction (publish -> fence -> tagged word; WG0 polls) ----
    if (wave == 0) {
        if (lane == 0) {
            float T = 0.f, E = 0.f;
#pragma unroll
            for (int w = 0; w < 16; ++w) { T += s_r0[w]; E += s_r1[w]; }
            const unsigned long long w1 =
                ((unsigned long long)__float_as_uint(T) << 32) | __float_as_uint(E);
            atomicExch(&pub2[wg], w1);
            __threadfence();               // payload visible before tag
            const unsigned long long w2 =
                ((unsigned long long)__float_as_uint(s_WS) << 32) | (unsigned long long)MAGIC;
            atomicExch(&pubF[wg], w2);
        }
        if (wg == 0) {                     // lanes 0..15 poll the 16 words in parallel
            const bool act = lane < K;
            unsigned long long w2 = 0ULL;
            for (;;) {
                if (act) w2 = atomicAdd(&pubF[lane], 0ULL);
                if (__all(!act || ((unsigned)w2 == MAGIC))) break;
            }
            __threadfence();
            const unsigned long long w1 = act ? atomicAdd(&pub2[lane], 0ULL) : 0ULL;
            float Tk = act ? __uint_as_float((unsigned)(w1 >> 32)) : 0.f;
            float Ek = act ? __uint_as_float((unsigned)w1)         : 0.f;
            float Wk = act ? __uint_as_float((unsigned)(w2 >> 32)) : 0.f;
#pragma unroll
            for (int o = 8; o; o >>= 1) {  // fold 16 lanes; higher lanes carry zeros
                Tk += __shfl_down(Tk, o, 64);
                Ek += __shfl_down(Ek, o, 64);
                Wk += __shfl_down(Wk, o, 64);
            }
            if (lane == 0) out[0] = -Tk / Ek + L2_REG * sqrtf(Wk);
        }
    }
}

extern "C" void kernel_launch(void* const* d_in, const int* in_sizes, int n_in,
                              void* d_out, int out_size, void* d_ws, size_t ws_size,
                              hipStream_t stream) {
    (void)in_sizes; (void)n_in; (void)out_size; (void)ws_size;
    unsigned long long* pub2 = (unsigned long long*)d_ws;  // [16] (T,E) packed
    unsigned long long* pubF = pub2 + K;                   // [16] (WS,MAGIC) packed

    cox_all<<<dim3(K), dim3(NT), 0, stream>>>((const float*)d_in[0],
                                              (const float*)d_in[1],
                                              (const int*)d_in[2],
                                              (const float*)d_in[3],
                                              pub2, pubF, (float*)d_out);
}